// Round 3
// baseline (673.014 us; speedup 1.0000x reference)
//
#include <hip/hip_runtime.h>
#include <hip/hip_bf16.h>

typedef __bf16 bf16x8 __attribute__((ext_vector_type(8)));
typedef __bf16 bf16x4 __attribute__((ext_vector_type(4)));
typedef float f32x4 __attribute__((ext_vector_type(4)));

#define EB 128    // edges per block
#define NSCAN 1024

// ---- ws layout (dword offsets) ----
#define OFF_COUNTS 0
#define OFF_CURSOR 100000
#define OFF_STARTS 200000
#define OFF_BSUM   300016
#define OFF_CSR    300160   // int2[E], then weights bf16[12288]

__device__ __forceinline__ unsigned short f2bf(float v) {
    unsigned int u = __float_as_uint(v);
    return (unsigned short)((u + 0x7fffu + ((u >> 16) & 1u)) >> 16);
}

__device__ __forceinline__ bf16x8 pack8(float4 a, float4 b) {
    bf16x8 r;
    r[0] = (__bf16)a.x; r[1] = (__bf16)a.y; r[2] = (__bf16)a.z; r[3] = (__bf16)a.w;
    r[4] = (__bf16)b.x; r[5] = (__bf16)b.y; r[6] = (__bf16)b.z; r[7] = (__bf16)b.w;
    return r;
}

__global__ void prep_weights_kernel(const float* __restrict__ W1,
                                    const float* __restrict__ W2,
                                    unsigned short* __restrict__ wout) {
    int t = blockIdx.x * blockDim.x + threadIdx.x;
    if (t < 8192) {
        int c = t >> 7, k = t & 127;
        wout[t] = f2bf(W1[k * 64 + c]);
    } else if (t < 12288) {
        int i = t - 8192;
        int o = i >> 6, c = i & 63;
        wout[t] = f2bf(W2[c * 64 + o]);
    }
}

__global__ void hist_kernel(const int* __restrict__ ei, int* __restrict__ counts, int E) {
    int t = blockIdx.x * blockDim.x + threadIdx.x;
    int i = t * 4;
    if (i + 3 < E) {
        int4 d = *(const int4*)(ei + E + i);
        atomicAdd(&counts[d.x], 1);
        atomicAdd(&counts[d.y], 1);
        atomicAdd(&counts[d.z], 1);
        atomicAdd(&counts[d.w], 1);
    } else {
        for (int j = 0; j < 4 && i + j < E; ++j)
            atomicAdd(&counts[ei[E + i + j]], 1);
    }
}

__global__ void scanA_kernel(const int* __restrict__ counts, int* __restrict__ bsum, int N) {
    int b = blockIdx.x, t = threadIdx.x;
    int base = b * NSCAN + t * 4;
    int s = 0;
    #pragma unroll
    for (int q = 0; q < 4; ++q)
        if (base + q < N) s += counts[base + q];
    #pragma unroll
    for (int off = 1; off < 64; off <<= 1) s += __shfl_xor(s, off);
    __shared__ int wsum[4];
    if ((t & 63) == 0) wsum[t >> 6] = s;
    __syncthreads();
    if (t == 0) bsum[b] = wsum[0] + wsum[1] + wsum[2] + wsum[3];
}

// single wave; nb <= 128
__global__ void scanB_kernel(int* __restrict__ bsum, int* __restrict__ starts, int nb, int N, int E) {
    int lane = threadIdx.x;
    int v0 = (lane < nb) ? bsum[lane] : 0;
    int v1 = (64 + lane < nb) ? bsum[64 + lane] : 0;
    int s = v0;
    #pragma unroll
    for (int off = 1; off < 64; off <<= 1) {
        int n = __shfl_up(s, off);
        if (lane >= off) s += n;
    }
    int total0 = __shfl(s, 63);
    int s1 = v1;
    #pragma unroll
    for (int off = 1; off < 64; off <<= 1) {
        int n = __shfl_up(s1, off);
        if (lane >= off) s1 += n;
    }
    if (lane < nb) bsum[lane] = s - v0;
    if (64 + lane < nb) bsum[64 + lane] = total0 + s1 - v1;
    if (lane == 0) starts[N] = E;
}

__global__ void scanC_kernel(const int* __restrict__ counts, const int* __restrict__ bsum,
                             int* __restrict__ starts, int* __restrict__ cursor, int N) {
    int b = blockIdx.x, t = threadIdx.x;
    int lane = t & 63, w = t >> 6;
    int base = b * NSCAN + t * 4;
    int c[4];
    #pragma unroll
    for (int q = 0; q < 4; ++q)
        c[q] = (base + q < N) ? counts[base + q] : 0;
    int tot = c[0] + c[1] + c[2] + c[3];
    int inc = tot;
    #pragma unroll
    for (int off = 1; off < 64; off <<= 1) {
        int n = __shfl_up(inc, off);
        if (lane >= off) inc += n;
    }
    int excl = inc - tot;
    __shared__ int wtot[4];
    if (lane == 63) wtot[w] = inc;
    __syncthreads();
    int woff = 0;
    for (int i = 0; i < w; ++i) woff += wtot[i];
    int run = bsum[b] + woff + excl;
    #pragma unroll
    for (int q = 0; q < 4; ++q) {
        if (base + q < N) { starts[base + q] = run; cursor[base + q] = run; run += c[q]; }
    }
}

__global__ void scatter_kernel(const int* __restrict__ ei, int* __restrict__ cursor,
                               int2* __restrict__ csr, int E) {
    int t = blockIdx.x * blockDim.x + threadIdx.x;
    if (t < E) {
        int s = ei[t], d = ei[E + t];
        int p = atomicAdd(&cursor[d], 1);
        csr[p] = make_int2(s, d);
    }
}

__global__ __launch_bounds__(512, 6)
void edgeconv_kernel(const float* __restrict__ x,
                     const int2* __restrict__ csr,
                     const int* __restrict__ starts,
                     const float* __restrict__ b1,
                     const float* __restrict__ b2,
                     const unsigned short* __restrict__ wbf,
                     float* __restrict__ out,
                     int E) {
    // sF: [128 edges][128 feat] bf16 (256B rows, XOR swizzle (e&7)<<4 on 16B chunks);
    //     reused after GEMM2 as h2 f32 [128][64] (same 256B rows, same swizzle).
    __shared__ __align__(16) unsigned char sF[EB * 256];
    __shared__ __align__(16) unsigned char sH[EB * 128];  // h1 bf16 [128][64]

    const int tid  = threadIdx.x;         // 0..511 (8 waves)
    const int lane = tid & 63;
    const int w    = tid >> 6;            // wave 0..7
    const int ln   = lane & 15;
    const int rg   = lane >> 4;           // 0..3
    const int p0   = blockIdx.x * EB;
    const int p1   = min(p0 + EB, E);

    // ---------------- gather (CSR order): F = [xi | xj - xi] bf16 ----------------
    {
        const int e = tid >> 2;           // 0..127 (wave-local rows: e in [w*16, w*16+16))
        const int q = tid & 3;            // quarter of the row
        const int p = p0 + e;
        int2 sd = make_int2(0, 0);
        if (p < E) sd = csr[p];

        const float4* xi4 = (const float4*)(x + (long)sd.y * 64 + q * 16);
        const float4* xj4 = (const float4*)(x + (long)sd.x * 64 + q * 16);
        float4 a0 = xi4[0], a1 = xi4[1], a2 = xi4[2], a3 = xi4[3];
        float4 c0 = xj4[0], c1 = xj4[1], c2 = xj4[2], c3 = xj4[3];

        unsigned char* rowp = sF + e * 256;
        const unsigned int swz = (unsigned int)(e & 7) << 4;
        *(bf16x8*)(rowp + (((unsigned)((q * 2 + 0) << 4)) ^ swz)) = pack8(a0, a1);
        *(bf16x8*)(rowp + (((unsigned)((q * 2 + 1) << 4)) ^ swz)) = pack8(a2, a3);
        float4 d0, d1, d2, d3;
        d0.x = c0.x - a0.x; d0.y = c0.y - a0.y; d0.z = c0.z - a0.z; d0.w = c0.w - a0.w;
        d1.x = c1.x - a1.x; d1.y = c1.y - a1.y; d1.z = c1.z - a1.z; d1.w = c1.w - a1.w;
        d2.x = c2.x - a2.x; d2.y = c2.y - a2.y; d2.z = c2.z - a2.z; d2.w = c2.w - a2.w;
        d3.x = c3.x - a3.x; d3.y = c3.y - a3.y; d3.z = c3.z - a3.z; d3.w = c3.w - a3.w;
        *(bf16x8*)(rowp + (((unsigned)((8 + q * 2 + 0) << 4)) ^ swz)) = pack8(d0, d1);
        *(bf16x8*)(rowp + (((unsigned)((8 + q * 2 + 1) << 4)) ^ swz)) = pack8(d2, d3);
    }

    // ---------------- weight fragments ----------------
    bf16x8 w1f[4][4];
    bf16x8 w2f[4][2];
    {
        const bf16x8* wsv = (const bf16x8*)wbf;
        #pragma unroll
        for (int ct = 0; ct < 4; ++ct)
            #pragma unroll
            for (int kt = 0; kt < 4; ++kt)
                w1f[ct][kt] = wsv[(ct * 16 + ln) * 16 + kt * 4 + rg];
        #pragma unroll
        for (int ot = 0; ot < 4; ++ot)
            #pragma unroll
            for (int kt = 0; kt < 2; ++kt)
                w2f[ot][kt] = wsv[1024 + (ot * 16 + ln) * 8 + kt * 4 + rg];
    }

    __syncthreads();

    const int e = w * 16 + ln;            // this wave's edge row for GEMMs
    const unsigned int swzE = (unsigned int)(e & 7) << 4;
    unsigned char* frow = sF + e * 256;
    unsigned char* hrow = sH + e * 128;

    // ---------------- GEMM1: H1^T = W1^T @ F^T (wave-local) ----------------
    f32x4 acc1[4];
    #pragma unroll
    for (int ct = 0; ct < 4; ++ct) acc1[ct] = (f32x4){0.f, 0.f, 0.f, 0.f};

    #pragma unroll
    for (int kt = 0; kt < 4; ++kt) {
        bf16x8 bfr = *(const bf16x8*)(frow + (((unsigned)(kt * 64 + rg * 16)) ^ swzE));
        #pragma unroll
        for (int ct = 0; ct < 4; ++ct)
            acc1[ct] = __builtin_amdgcn_mfma_f32_16x16x32_bf16(
                w1f[ct][kt], bfr, acc1[ct], 0, 0, 0);
    }

    // ---------------- epilogue1: bias+relu -> bf16 -> sH (wave-local) ----------------
    #pragma unroll
    for (int ct = 0; ct < 4; ++ct) {
        const int c0 = ct * 16 + rg * 4;
        float4 bv = *(const float4*)(b1 + c0);
        bf16x4 hv;
        hv[0] = (__bf16)fmaxf(acc1[ct][0] + bv.x, 0.f);
        hv[1] = (__bf16)fmaxf(acc1[ct][1] + bv.y, 0.f);
        hv[2] = (__bf16)fmaxf(acc1[ct][2] + bv.z, 0.f);
        hv[3] = (__bf16)fmaxf(acc1[ct][3] + bv.w, 0.f);
        *(bf16x4*)(hrow + (((unsigned)(c0 * 2)) ^ swzE)) = hv;
    }

    // ---------------- GEMM2: H2^T = W2^T @ H1^T (wave-local) ----------------
    f32x4 acc2[4];
    #pragma unroll
    for (int ot = 0; ot < 4; ++ot) acc2[ot] = (f32x4){0.f, 0.f, 0.f, 0.f};

    #pragma unroll
    for (int kt = 0; kt < 2; ++kt) {
        bf16x8 bfr = *(const bf16x8*)(hrow + (((unsigned)(kt * 64 + rg * 16)) ^ swzE));
        #pragma unroll
        for (int ot = 0; ot < 4; ++ot)
            acc2[ot] = __builtin_amdgcn_mfma_f32_16x16x32_bf16(
                w2f[ot][kt], bfr, acc2[ot], 0, 0, 0);
    }

    // ---------------- epilogue2: bias+relu -> f32 into sF (wave-local) ----------------
    #pragma unroll
    for (int ot = 0; ot < 4; ++ot) {
        const int c0 = ot * 16 + rg * 4;
        float4 bv = *(const float4*)(b2 + c0);
        f32x4 v;
        v[0] = fmaxf(acc2[ot][0] + bv.x, 0.f);
        v[1] = fmaxf(acc2[ot][1] + bv.y, 0.f);
        v[2] = fmaxf(acc2[ot][2] + bv.z, 0.f);
        v[3] = fmaxf(acc2[ot][3] + bv.w, 0.f);
        *(f32x4*)(frow + (((unsigned)(c0 * 4)) ^ swzE)) = v;
    }

    __syncthreads();

    // ---------------- segmented max over dst groups ----------------
    {
        const int dfirst = csr[p0].y;
        const int dlast  = csr[p1 - 1].y;
        const int c = lane;
        for (int d = dfirst + w; d <= dlast; d += 8) {
            const int s0 = starts[d], s1 = starts[d + 1];
            const int lo = max(s0, p0), hi = min(s1, p1);
            if (lo >= hi) continue;  // zero-edge node inside range
            float m = 0.0f;          // relu >= 0; empty -> 0 matches reference
            for (int p = lo; p < hi; ++p) {
                const int ee = p - p0;
                m = fmaxf(m, *(const float*)(sF + ee * 256 +
                            (((unsigned)(c * 4)) ^ ((unsigned)(ee & 7) << 4))));
            }
            if (s0 >= p0 && s1 <= p1)
                out[(long)d * 64 + c] = m;                                   // sole owner
            else
                atomicMax((int*)out + (long)d * 64 + c, __float_as_int(m));  // boundary
        }
    }
}

extern "C" void kernel_launch(void* const* d_in, const int* in_sizes, int n_in,
                              void* d_out, int out_size, void* d_ws, size_t ws_size,
                              hipStream_t stream) {
    const float* x  = (const float*)d_in[0];
    const int*   ei = (const int*)d_in[1];
    const float* W1 = (const float*)d_in[2];
    const float* b1 = (const float*)d_in[3];
    const float* W2 = (const float*)d_in[4];
    const float* b2 = (const float*)d_in[5];
    float* out = (float*)d_out;

    const int E = in_sizes[1] / 2;
    const int N = in_sizes[0] / 64;

    int* wsI = (int*)d_ws;
    int* counts  = wsI + OFF_COUNTS;
    int* cursor  = wsI + OFF_CURSOR;
    int* starts  = wsI + OFF_STARTS;
    int* bsum    = wsI + OFF_BSUM;
    int2* csr    = (int2*)(wsI + OFF_CSR);
    unsigned short* wbf = (unsigned short*)(wsI + OFF_CSR + 2 * E);

    hipMemsetAsync(d_out, 0, (size_t)out_size * sizeof(float), stream);
    hipMemsetAsync(counts, 0, (size_t)N * sizeof(int), stream);

    prep_weights_kernel<<<48, 256, 0, stream>>>(W1, W2, wbf);

    const int nbH = (E / 4 + 255) / 256 + 1;
    hist_kernel<<<nbH, 256, 0, stream>>>(ei, counts, E);

    const int nb2 = (N + NSCAN - 1) / NSCAN;
    scanA_kernel<<<nb2, 256, 0, stream>>>(counts, bsum, N);
    scanB_kernel<<<1, 64, 0, stream>>>(bsum, starts, nb2, N, E);
    scanC_kernel<<<nb2, 256, 0, stream>>>(counts, bsum, starts, cursor, N);

    const int nbE = (E + 255) / 256;
    scatter_kernel<<<nbE, 256, 0, stream>>>(ei, cursor, csr, E);

    const int nb = (E + EB - 1) / EB;
    edgeconv_kernel<<<nb, 512, 0, stream>>>(x, csr, starts, b1, b2, wbf, out, E);
}

// Round 4
// 544.130 us; speedup vs baseline: 1.2369x; 1.2369x over previous
//
#include <hip/hip_runtime.h>
#include <hip/hip_bf16.h>

typedef __bf16 bf16x8 __attribute__((ext_vector_type(8)));
typedef __bf16 bf16x4 __attribute__((ext_vector_type(4)));
typedef float f32x4 __attribute__((ext_vector_type(4)));

#define EB 128    // edges per block
#define NSCAN 1024

// ---- ws layout (dword offsets) ----
#define OFF_COUNTS 0
#define OFF_CURSOR 100000
#define OFF_STARTS 200000
#define OFF_BSUM   300016
#define OFF_CSR    300160   // int2[E], then weights bf16[12288]

__device__ __forceinline__ unsigned short f2bf(float v) {
    unsigned int u = __float_as_uint(v);
    return (unsigned short)((u + 0x7fffu + ((u >> 16) & 1u)) >> 16);
}

__device__ __forceinline__ bf16x8 pack8(float4 a, float4 b) {
    bf16x8 r;
    r[0] = (__bf16)a.x; r[1] = (__bf16)a.y; r[2] = (__bf16)a.z; r[3] = (__bf16)a.w;
    r[4] = (__bf16)b.x; r[5] = (__bf16)b.y; r[6] = (__bf16)b.z; r[7] = (__bf16)b.w;
    return r;
}

__global__ void prep_weights_kernel(const float* __restrict__ W1,
                                    const float* __restrict__ W2,
                                    unsigned short* __restrict__ wout) {
    int t = blockIdx.x * blockDim.x + threadIdx.x;
    if (t < 8192) {
        int c = t >> 7, k = t & 127;
        wout[t] = f2bf(W1[k * 64 + c]);
    } else if (t < 12288) {
        int i = t - 8192;
        int o = i >> 6, c = i & 63;
        wout[t] = f2bf(W2[c * 64 + o]);
    }
}

__global__ void hist_kernel(const int* __restrict__ ei, int* __restrict__ counts, int E) {
    int t = blockIdx.x * blockDim.x + threadIdx.x;
    int i = t * 4;
    if (i + 3 < E) {
        int4 d = *(const int4*)(ei + E + i);
        atomicAdd(&counts[d.x], 1);
        atomicAdd(&counts[d.y], 1);
        atomicAdd(&counts[d.z], 1);
        atomicAdd(&counts[d.w], 1);
    } else {
        for (int j = 0; j < 4 && i + j < E; ++j)
            atomicAdd(&counts[ei[E + i + j]], 1);
    }
}

__global__ void scanA_kernel(const int* __restrict__ counts, int* __restrict__ bsum, int N) {
    int b = blockIdx.x, t = threadIdx.x;
    int base = b * NSCAN + t * 4;
    int s = 0;
    #pragma unroll
    for (int q = 0; q < 4; ++q)
        if (base + q < N) s += counts[base + q];
    #pragma unroll
    for (int off = 1; off < 64; off <<= 1) s += __shfl_xor(s, off);
    __shared__ int wsum[4];
    if ((t & 63) == 0) wsum[t >> 6] = s;
    __syncthreads();
    if (t == 0) bsum[b] = wsum[0] + wsum[1] + wsum[2] + wsum[3];
}

// single wave; nb <= 128
__global__ void scanB_kernel(int* __restrict__ bsum, int* __restrict__ starts, int nb, int N, int E) {
    int lane = threadIdx.x;
    int v0 = (lane < nb) ? bsum[lane] : 0;
    int v1 = (64 + lane < nb) ? bsum[64 + lane] : 0;
    int s = v0;
    #pragma unroll
    for (int off = 1; off < 64; off <<= 1) {
        int n = __shfl_up(s, off);
        if (lane >= off) s += n;
    }
    int total0 = __shfl(s, 63);
    int s1 = v1;
    #pragma unroll
    for (int off = 1; off < 64; off <<= 1) {
        int n = __shfl_up(s1, off);
        if (lane >= off) s1 += n;
    }
    if (lane < nb) bsum[lane] = s - v0;
    if (64 + lane < nb) bsum[64 + lane] = total0 + s1 - v1;
    if (lane == 0) starts[N] = E;
}

__global__ void scanC_kernel(const int* __restrict__ counts, const int* __restrict__ bsum,
                             int* __restrict__ starts, int* __restrict__ cursor, int N) {
    int b = blockIdx.x, t = threadIdx.x;
    int lane = t & 63, w = t >> 6;
    int base = b * NSCAN + t * 4;
    int c[4];
    #pragma unroll
    for (int q = 0; q < 4; ++q)
        c[q] = (base + q < N) ? counts[base + q] : 0;
    int tot = c[0] + c[1] + c[2] + c[3];
    int inc = tot;
    #pragma unroll
    for (int off = 1; off < 64; off <<= 1) {
        int n = __shfl_up(inc, off);
        if (lane >= off) inc += n;
    }
    int excl = inc - tot;
    __shared__ int wtot[4];
    if (lane == 63) wtot[w] = inc;
    __syncthreads();
    int woff = 0;
    for (int i = 0; i < w; ++i) woff += wtot[i];
    int run = bsum[b] + woff + excl;
    #pragma unroll
    for (int q = 0; q < 4; ++q) {
        if (base + q < N) { starts[base + q] = run; cursor[base + q] = run; run += c[q]; }
    }
}

__global__ void scatter_kernel(const int* __restrict__ ei, int* __restrict__ cursor,
                               int2* __restrict__ csr, int E) {
    int t = blockIdx.x * blockDim.x + threadIdx.x;
    if (t < E) {
        int s = ei[t], d = ei[E + t];
        int p = atomicAdd(&cursor[d], 1);
        csr[p] = make_int2(s, d);
    }
}

__global__ __launch_bounds__(512, 6)
void edgeconv_kernel(const float* __restrict__ x,
                     const int2* __restrict__ csr,
                     const int* __restrict__ starts,
                     const float* __restrict__ b1,
                     const float* __restrict__ b2,
                     const unsigned short* __restrict__ wbf,
                     float* __restrict__ out,
                     int E) {
    // sF: [128 edges][128 feat] bf16 (256B rows, XOR swizzle (e&7)<<4 on 16B chunks);
    //     reused after GEMM2 as h2 f32 [128][64] (same 256B rows, same swizzle).
    __shared__ __align__(16) unsigned char sF[EB * 256];
    __shared__ __align__(16) unsigned char sH[EB * 128];  // h1 bf16 [128][64]

    const int tid  = threadIdx.x;         // 0..511 (8 waves)
    const int lane = tid & 63;
    const int w    = tid >> 6;            // wave 0..7
    const int ln   = lane & 15;
    const int rg   = lane >> 4;           // 0..3
    const int p0   = blockIdx.x * EB;
    const int p1   = min(p0 + EB, E);

    // weight fragment pointers (streamed at MFMA time; 24KB total, L1-resident;
    // each fragment is used exactly once per wave -> registers buy nothing)
    const bf16x8* wsv = (const bf16x8*)wbf;

    // ---------------- gather (CSR order): F = [xi | xj - xi] bf16 ----------------
    {
        const int e = tid >> 2;           // 0..127
        const int q = tid & 3;            // quarter of the row
        const int p = p0 + e;
        int2 sd = make_int2(0, 0);
        if (p < E) sd = csr[p];

        const float4* xi4 = (const float4*)(x + (long)sd.y * 64 + q * 16);
        const float4* xj4 = (const float4*)(x + (long)sd.x * 64 + q * 16);
        float4 a0 = xi4[0], a1 = xi4[1], a2 = xi4[2], a3 = xi4[3];
        float4 c0 = xj4[0], c1 = xj4[1], c2 = xj4[2], c3 = xj4[3];

        unsigned char* rowp = sF + e * 256;
        const unsigned int swz = (unsigned int)(e & 7) << 4;
        *(bf16x8*)(rowp + (((unsigned)((q * 2 + 0) << 4)) ^ swz)) = pack8(a0, a1);
        *(bf16x8*)(rowp + (((unsigned)((q * 2 + 1) << 4)) ^ swz)) = pack8(a2, a3);
        float4 d0, d1, d2, d3;
        d0.x = c0.x - a0.x; d0.y = c0.y - a0.y; d0.z = c0.z - a0.z; d0.w = c0.w - a0.w;
        d1.x = c1.x - a1.x; d1.y = c1.y - a1.y; d1.z = c1.z - a1.z; d1.w = c1.w - a1.w;
        d2.x = c2.x - a2.x; d2.y = c2.y - a2.y; d2.z = c2.z - a2.z; d2.w = c2.w - a2.w;
        d3.x = c3.x - a3.x; d3.y = c3.y - a3.y; d3.z = c3.z - a3.z; d3.w = c3.w - a3.w;
        *(bf16x8*)(rowp + (((unsigned)((8 + q * 2 + 0) << 4)) ^ swz)) = pack8(d0, d1);
        *(bf16x8*)(rowp + (((unsigned)((8 + q * 2 + 1) << 4)) ^ swz)) = pack8(d2, d3);
    }

    __syncthreads();

    const int e = w * 16 + ln;            // this wave's edge row for GEMMs
    const unsigned int swzE = (unsigned int)(e & 7) << 4;
    unsigned char* frow = sF + e * 256;
    unsigned char* hrow = sH + e * 128;

    // ---------------- GEMM1: H1^T = W1^T @ F^T (wave-local) ----------------
    f32x4 acc1[4];
    #pragma unroll
    for (int ct = 0; ct < 4; ++ct) acc1[ct] = (f32x4){0.f, 0.f, 0.f, 0.f};

    #pragma unroll
    for (int kt = 0; kt < 4; ++kt) {
        bf16x8 bfr = *(const bf16x8*)(frow + (((unsigned)(kt * 64 + rg * 16)) ^ swzE));
        #pragma unroll
        for (int ct = 0; ct < 4; ++ct) {
            bf16x8 wf = wsv[(ct * 16 + ln) * 16 + kt * 4 + rg];
            acc1[ct] = __builtin_amdgcn_mfma_f32_16x16x32_bf16(wf, bfr, acc1[ct], 0, 0, 0);
        }
    }

    // ---------------- epilogue1: bias+relu -> bf16 -> sH (wave-local) ----------------
    #pragma unroll
    for (int ct = 0; ct < 4; ++ct) {
        const int c0 = ct * 16 + rg * 4;
        float4 bv = *(const float4*)(b1 + c0);
        bf16x4 hv;
        hv[0] = (__bf16)fmaxf(acc1[ct][0] + bv.x, 0.f);
        hv[1] = (__bf16)fmaxf(acc1[ct][1] + bv.y, 0.f);
        hv[2] = (__bf16)fmaxf(acc1[ct][2] + bv.z, 0.f);
        hv[3] = (__bf16)fmaxf(acc1[ct][3] + bv.w, 0.f);
        *(bf16x4*)(hrow + (((unsigned)(c0 * 2)) ^ swzE)) = hv;
    }

    // ---------------- GEMM2: H2^T = W2^T @ H1^T (wave-local) ----------------
    f32x4 acc2[4];
    #pragma unroll
    for (int ot = 0; ot < 4; ++ot) acc2[ot] = (f32x4){0.f, 0.f, 0.f, 0.f};

    #pragma unroll
    for (int kt = 0; kt < 2; ++kt) {
        bf16x8 bfr = *(const bf16x8*)(hrow + (((unsigned)(kt * 64 + rg * 16)) ^ swzE));
        #pragma unroll
        for (int ot = 0; ot < 4; ++ot) {
            bf16x8 wf = wsv[1024 + (ot * 16 + ln) * 8 + kt * 4 + rg];
            acc2[ot] = __builtin_amdgcn_mfma_f32_16x16x32_bf16(wf, bfr, acc2[ot], 0, 0, 0);
        }
    }

    // ---------------- epilogue2: bias+relu -> f32 into sF (wave-local) ----------------
    #pragma unroll
    for (int ot = 0; ot < 4; ++ot) {
        const int c0 = ot * 16 + rg * 4;
        float4 bv = *(const float4*)(b2 + c0);
        f32x4 v;
        v[0] = fmaxf(acc2[ot][0] + bv.x, 0.f);
        v[1] = fmaxf(acc2[ot][1] + bv.y, 0.f);
        v[2] = fmaxf(acc2[ot][2] + bv.z, 0.f);
        v[3] = fmaxf(acc2[ot][3] + bv.w, 0.f);
        *(f32x4*)(frow + (((unsigned)(c0 * 4)) ^ swzE)) = v;
    }

    __syncthreads();

    // ---------------- segmented max over dst groups ----------------
    {
        const int dfirst = csr[p0].y;
        const int dlast  = csr[p1 - 1].y;
        const int c = lane;
        for (int d = dfirst + w; d <= dlast; d += 8) {
            const int s0 = starts[d], s1 = starts[d + 1];
            const int lo = max(s0, p0), hi = min(s1, p1);
            if (lo >= hi) continue;  // zero-edge node inside range
            float m = 0.0f;          // relu >= 0; empty -> 0 matches reference
            for (int p = lo; p < hi; ++p) {
                const int ee = p - p0;
                m = fmaxf(m, *(const float*)(sF + ee * 256 +
                            (((unsigned)(c * 4)) ^ ((unsigned)(ee & 7) << 4))));
            }
            if (s0 >= p0 && s1 <= p1)
                out[(long)d * 64 + c] = m;                                   // sole owner
            else
                atomicMax((int*)out + (long)d * 64 + c, __float_as_int(m));  // boundary
        }
    }
}

extern "C" void kernel_launch(void* const* d_in, const int* in_sizes, int n_in,
                              void* d_out, int out_size, void* d_ws, size_t ws_size,
                              hipStream_t stream) {
    const float* x  = (const float*)d_in[0];
    const int*   ei = (const int*)d_in[1];
    const float* W1 = (const float*)d_in[2];
    const float* b1 = (const float*)d_in[3];
    const float* W2 = (const float*)d_in[4];
    const float* b2 = (const float*)d_in[5];
    float* out = (float*)d_out;

    const int E = in_sizes[1] / 2;
    const int N = in_sizes[0] / 64;

    int* wsI = (int*)d_ws;
    int* counts  = wsI + OFF_COUNTS;
    int* cursor  = wsI + OFF_CURSOR;
    int* starts  = wsI + OFF_STARTS;
    int* bsum    = wsI + OFF_BSUM;
    int2* csr    = (int2*)(wsI + OFF_CSR);
    unsigned short* wbf = (unsigned short*)(wsI + OFF_CSR + 2 * E);

    hipMemsetAsync(d_out, 0, (size_t)out_size * sizeof(float), stream);
    hipMemsetAsync(counts, 0, (size_t)N * sizeof(int), stream);

    prep_weights_kernel<<<48, 256, 0, stream>>>(W1, W2, wbf);

    const int nbH = (E / 4 + 255) / 256 + 1;
    hist_kernel<<<nbH, 256, 0, stream>>>(ei, counts, E);

    const int nb2 = (N + NSCAN - 1) / NSCAN;
    scanA_kernel<<<nb2, 256, 0, stream>>>(counts, bsum, N);
    scanB_kernel<<<1, 64, 0, stream>>>(bsum, starts, nb2, N, E);
    scanC_kernel<<<nb2, 256, 0, stream>>>(counts, bsum, starts, cursor, N);

    const int nbE = (E + 255) / 256;
    scatter_kernel<<<nbE, 256, 0, stream>>>(ei, cursor, csr, E);

    const int nb = (E + EB - 1) / EB;
    edgeconv_kernel<<<nb, 512, 0, stream>>>(x, csr, starts, b1, b2, wbf, out, E);
}

// Round 6
// 422.526 us; speedup vs baseline: 1.5928x; 1.2878x over previous
//
#include <hip/hip_runtime.h>
#include <hip/hip_bf16.h>

typedef __bf16 bf16x8 __attribute__((ext_vector_type(8)));
typedef __bf16 bf16x4 __attribute__((ext_vector_type(4)));
typedef float f32x4 __attribute__((ext_vector_type(4)));

#define EB 128    // edges per block
#define NSCAN 1024

// ---- ws layout (dword offsets) ----
#define OFF_COUNTS 0
#define OFF_CURSOR 100000
#define OFF_STARTS 200000
#define OFF_BSUM   300016
#define OFF_CSR    300160                 // int2[E] = 2E dwords
#define WBF_DW     6144                   // 12288 bf16 = 6144 dwords
// wbf (bf16[12288]) at OFF_CSR + 2E      [6144 dwords]
// xbf (bf16[N*64])  at OFF_CSR + 2E + WBF_DW

__device__ __forceinline__ unsigned short f2bf(float v) {
    unsigned int u = __float_as_uint(v);
    return (unsigned short)((u + 0x7fffu + ((u >> 16) & 1u)) >> 16);
}

__device__ __forceinline__ bf16x8 pack8(float4 a, float4 b) {
    bf16x8 r;
    r[0] = (__bf16)a.x; r[1] = (__bf16)a.y; r[2] = (__bf16)a.z; r[3] = (__bf16)a.w;
    r[4] = (__bf16)b.x; r[5] = (__bf16)b.y; r[6] = (__bf16)b.z; r[7] = (__bf16)b.w;
    return r;
}

// blocks [0,48): weight transpose+cvt; blocks [48, ...): x -> bf16
__global__ void prep_all_kernel(const float* __restrict__ x,
                                const float* __restrict__ W1,
                                const float* __restrict__ W2,
                                unsigned short* __restrict__ wbf,
                                unsigned short* __restrict__ xbf,
                                long nOct, int use_bf) {
    int b = blockIdx.x;
    if (b < 48) {
        int t = b * 256 + threadIdx.x;
        if (t < 8192) {
            int c = t >> 7, k = t & 127;
            wbf[t] = f2bf(W1[k * 64 + c]);
        } else if (t < 12288) {
            int i = t - 8192;
            int o = i >> 6, c = i & 63;
            wbf[t] = f2bf(W2[c * 64 + o]);
        }
    } else if (use_bf) {
        long i = (long)(b - 48) * 256 + threadIdx.x;   // octet index
        if (i < nOct) {
            float4 a = *(const float4*)(x + i * 8);
            float4 c = *(const float4*)(x + i * 8 + 4);
            *(bf16x8*)(xbf + i * 8) = pack8(a, c);
        }
    }
}

__global__ void hist_kernel(const int* __restrict__ ei, int* __restrict__ counts, int E) {
    int t = blockIdx.x * blockDim.x + threadIdx.x;
    int i = t * 4;
    if (i + 3 < E) {
        int4 d = *(const int4*)(ei + E + i);
        atomicAdd(&counts[d.x], 1);
        atomicAdd(&counts[d.y], 1);
        atomicAdd(&counts[d.z], 1);
        atomicAdd(&counts[d.w], 1);
    } else {
        for (int j = 0; j < 4 && i + j < E; ++j)
            atomicAdd(&counts[ei[E + i + j]], 1);
    }
}

__global__ void scanA_kernel(const int* __restrict__ counts, int* __restrict__ bsum, int N) {
    int b = blockIdx.x, t = threadIdx.x;
    int base = b * NSCAN + t * 4;
    int s = 0;
    #pragma unroll
    for (int q = 0; q < 4; ++q)
        if (base + q < N) s += counts[base + q];
    #pragma unroll
    for (int off = 1; off < 64; off <<= 1) s += __shfl_xor(s, off);
    __shared__ int wsum[4];
    if ((t & 63) == 0) wsum[t >> 6] = s;
    __syncthreads();
    if (t == 0) bsum[b] = wsum[0] + wsum[1] + wsum[2] + wsum[3];
}

// single wave; nb <= 128
__global__ void scanB_kernel(int* __restrict__ bsum, int* __restrict__ starts, int nb, int N, int E) {
    int lane = threadIdx.x;
    int v0 = (lane < nb) ? bsum[lane] : 0;
    int v1 = (64 + lane < nb) ? bsum[64 + lane] : 0;
    int s = v0;
    #pragma unroll
    for (int off = 1; off < 64; off <<= 1) {
        int n = __shfl_up(s, off);
        if (lane >= off) s += n;
    }
    int total0 = __shfl(s, 63);
    int s1 = v1;
    #pragma unroll
    for (int off = 1; off < 64; off <<= 1) {
        int n = __shfl_up(s1, off);
        if (lane >= off) s1 += n;
    }
    if (lane < nb) bsum[lane] = s - v0;
    if (64 + lane < nb) bsum[64 + lane] = total0 + s1 - v1;
    if (lane == 0) starts[N] = E;
}

__global__ void scanC_kernel(const int* __restrict__ counts, const int* __restrict__ bsum,
                             int* __restrict__ starts, int* __restrict__ cursor, int N) {
    int b = blockIdx.x, t = threadIdx.x;
    int lane = t & 63, w = t >> 6;
    int base = b * NSCAN + t * 4;
    int c[4];
    #pragma unroll
    for (int q = 0; q < 4; ++q)
        c[q] = (base + q < N) ? counts[base + q] : 0;
    int tot = c[0] + c[1] + c[2] + c[3];
    int inc = tot;
    #pragma unroll
    for (int off = 1; off < 64; off <<= 1) {
        int n = __shfl_up(inc, off);
        if (lane >= off) inc += n;
    }
    int excl = inc - tot;
    __shared__ int wtot[4];
    if (lane == 63) wtot[w] = inc;
    __syncthreads();
    int woff = 0;
    for (int i = 0; i < w; ++i) woff += wtot[i];
    int run = bsum[b] + woff + excl;
    #pragma unroll
    for (int q = 0; q < 4; ++q) {
        if (base + q < N) { starts[base + q] = run; cursor[base + q] = run; run += c[q]; }
    }
}

__global__ void scatter_kernel(const int* __restrict__ ei, int* __restrict__ cursor,
                               int2* __restrict__ csr, int E) {
    int t = blockIdx.x * blockDim.x + threadIdx.x;
    if (t < E) {
        int s = ei[t], d = ei[E + t];
        int p = atomicAdd(&cursor[d], 1);
        csr[p] = make_int2(s, d);
    }
}

__global__ __launch_bounds__(256, 4)
void edgeconv_kernel(const float* __restrict__ x,
                     const unsigned short* __restrict__ xbf,  // may be null
                     const int2* __restrict__ csr,
                     const int* __restrict__ starts,
                     const float* __restrict__ b1,
                     const float* __restrict__ b2,
                     const unsigned short* __restrict__ wbf,
                     float* __restrict__ out,
                     int E, int use_bf) {
    // sB: union — h1 bf16 [128][64] in first 16KB (rows 128B, XOR swizzle
    // (e&7)<<4 on 16B chunks), then (after barrier) h2 f32 [128][64]
    // (rows 256B, same swizzle).
    __shared__ __align__(16) unsigned char sB[EB * 256];

    const int tid  = threadIdx.x;         // 0..255 (4 waves)
    const int lane = tid & 63;
    const int w    = tid >> 6;            // wave 0..3
    const int ln   = lane & 15;
    const int rg   = lane >> 4;           // 0..3
    const int p0   = blockIdx.x * EB;
    const int p1   = min(p0 + EB, E);

    const bf16x8* wsv = (const bf16x8*)wbf;

    // ---------------- gather: B-fragments straight into registers ----------------
    // Wave w owns edges e = (2w+eti)*16 + ln; lane (ln,rg) needs channels
    // [rg*8, rg*8+8) and [32+rg*8, ...) of xi and (xj-xi)  -> 4 frags per tile.
    bf16x8 fr[2][4];
    #pragma unroll
    for (int eti = 0; eti < 2; ++eti) {
        const int p = p0 + (w * 2 + eti) * 16 + ln;
        int2 sd = (p < E) ? csr[p] : make_int2(0, 0);
        if (use_bf) {
            const unsigned short* xi = xbf + (long)sd.y * 64;
            const unsigned short* xj = xbf + (long)sd.x * 64;
            bf16x8 xiA = *(const bf16x8*)(xi + rg * 8);
            bf16x8 xiB = *(const bf16x8*)(xi + 32 + rg * 8);
            bf16x8 xjA = *(const bf16x8*)(xj + rg * 8);
            bf16x8 xjB = *(const bf16x8*)(xj + 32 + rg * 8);
            fr[eti][0] = xiA;
            fr[eti][1] = xiB;
            #pragma unroll
            for (int j = 0; j < 8; ++j) {
                fr[eti][2][j] = (__bf16)((float)xjA[j] - (float)xiA[j]);
                fr[eti][3][j] = (__bf16)((float)xjB[j] - (float)xiB[j]);
            }
        } else {
            const float* xi = x + (long)sd.y * 64;
            const float* xj = x + (long)sd.x * 64;
            float4 a0 = *(const float4*)(xi + rg * 8),      a1 = *(const float4*)(xi + rg * 8 + 4);
            float4 a2 = *(const float4*)(xi + 32 + rg * 8), a3 = *(const float4*)(xi + 32 + rg * 8 + 4);
            float4 c0 = *(const float4*)(xj + rg * 8),      c1 = *(const float4*)(xj + rg * 8 + 4);
            float4 c2 = *(const float4*)(xj + 32 + rg * 8), c3 = *(const float4*)(xj + 32 + rg * 8 + 4);
            fr[eti][0] = pack8(a0, a1);
            fr[eti][1] = pack8(a2, a3);
            float4 d0, d1, d2, d3;
            d0.x = c0.x - a0.x; d0.y = c0.y - a0.y; d0.z = c0.z - a0.z; d0.w = c0.w - a0.w;
            d1.x = c1.x - a1.x; d1.y = c1.y - a1.y; d1.z = c1.z - a1.z; d1.w = c1.w - a1.w;
            d2.x = c2.x - a2.x; d2.y = c2.y - a2.y; d2.z = c2.z - a2.z; d2.w = c2.w - a2.w;
            d3.x = c3.x - a3.x; d3.y = c3.y - a3.y; d3.z = c3.z - a3.z; d3.w = c3.w - a3.w;
            fr[eti][2] = pack8(d0, d1);
            fr[eti][3] = pack8(d2, d3);
        }
    }

    // ---------------- GEMM1: H1^T = W1^T @ F^T (B from registers) ----------------
    f32x4 acc1[2][4];
    #pragma unroll
    for (int eti = 0; eti < 2; ++eti)
        #pragma unroll
        for (int ct = 0; ct < 4; ++ct)
            acc1[eti][ct] = (f32x4){0.f, 0.f, 0.f, 0.f};

    #pragma unroll
    for (int kt = 0; kt < 4; ++kt) {
        #pragma unroll
        for (int ct = 0; ct < 4; ++ct) {
            bf16x8 wf = wsv[(ct * 16 + ln) * 16 + kt * 4 + rg];
            acc1[0][ct] = __builtin_amdgcn_mfma_f32_16x16x32_bf16(wf, fr[0][kt], acc1[0][ct], 0, 0, 0);
            acc1[1][ct] = __builtin_amdgcn_mfma_f32_16x16x32_bf16(wf, fr[1][kt], acc1[1][ct], 0, 0, 0);
        }
    }

    // ---------------- epilogue1: bias+relu -> bf16 -> h1 in sB (wave-local) ----------------
    #pragma unroll
    for (int eti = 0; eti < 2; ++eti) {
        const int e = (w * 2 + eti) * 16 + ln;
        unsigned char* rowp = sB + e * 128;
        const unsigned int swz = (unsigned int)(e & 7) << 4;
        #pragma unroll
        for (int ct = 0; ct < 4; ++ct) {
            const int c0 = ct * 16 + rg * 4;
            float4 bv = *(const float4*)(b1 + c0);
            bf16x4 hv;
            hv[0] = (__bf16)fmaxf(acc1[eti][ct][0] + bv.x, 0.f);
            hv[1] = (__bf16)fmaxf(acc1[eti][ct][1] + bv.y, 0.f);
            hv[2] = (__bf16)fmaxf(acc1[eti][ct][2] + bv.z, 0.f);
            hv[3] = (__bf16)fmaxf(acc1[eti][ct][3] + bv.w, 0.f);
            *(bf16x4*)(rowp + (((unsigned)(c0 * 2)) ^ swz)) = hv;
        }
    }

    // ---------------- GEMM2: H2^T = W2^T @ H1^T (h1 read is wave-local) ----------------
    f32x4 acc2[2][4];
    #pragma unroll
    for (int eti = 0; eti < 2; ++eti)
        #pragma unroll
        for (int ot = 0; ot < 4; ++ot)
            acc2[eti][ot] = (f32x4){0.f, 0.f, 0.f, 0.f};

    #pragma unroll
    for (int kt = 0; kt < 2; ++kt) {
        #pragma unroll
        for (int eti = 0; eti < 2; ++eti) {
            const int e = (w * 2 + eti) * 16 + ln;
            bf16x8 bfr = *(const bf16x8*)(sB + e * 128 +
                           (((unsigned)(kt * 64 + rg * 16)) ^ ((unsigned)(e & 7) << 4)));
            #pragma unroll
            for (int ot = 0; ot < 4; ++ot) {
                bf16x8 wf = wsv[1024 + (ot * 16 + ln) * 8 + kt * 4 + rg];
                acc2[eti][ot] = __builtin_amdgcn_mfma_f32_16x16x32_bf16(wf, bfr, acc2[eti][ot], 0, 0, 0);
            }
        }
    }

    __syncthreads();   // everyone done reading h1 before h2 overwrites sB

    // ---------------- epilogue2: bias+relu -> f32 h2 in sB ----------------
    #pragma unroll
    for (int eti = 0; eti < 2; ++eti) {
        const int e = (w * 2 + eti) * 16 + ln;
        unsigned char* rowp = sB + e * 256;
        const unsigned int swz = (unsigned int)(e & 7) << 4;
        #pragma unroll
        for (int ot = 0; ot < 4; ++ot) {
            const int c0 = ot * 16 + rg * 4;
            float4 bv = *(const float4*)(b2 + c0);
            f32x4 v;
            v[0] = fmaxf(acc2[eti][ot][0] + bv.x, 0.f);
            v[1] = fmaxf(acc2[eti][ot][1] + bv.y, 0.f);
            v[2] = fmaxf(acc2[eti][ot][2] + bv.z, 0.f);
            v[3] = fmaxf(acc2[eti][ot][3] + bv.w, 0.f);
            *(f32x4*)(rowp + (((unsigned)(c0 * 4)) ^ swz)) = v;
        }
    }

    __syncthreads();

    // ---------------- segmented max over dst groups ----------------
    {
        const int dfirst = csr[p0].y;
        const int dlast  = csr[p1 - 1].y;
        const int c = lane;
        for (int d = dfirst + w; d <= dlast; d += 4) {
            const int s0 = starts[d], s1 = starts[d + 1];
            const int lo = max(s0, p0), hi = min(s1, p1);
            if (lo >= hi) continue;  // zero-edge node inside range
            float m0 = 0.0f, m1 = 0.0f;   // relu >= 0; empty -> 0 matches reference
            int p = lo;
            for (; p + 1 < hi; p += 2) {
                const int e0 = p - p0, e1 = e0 + 1;
                m0 = fmaxf(m0, *(const float*)(sB + e0 * 256 +
                             (((unsigned)(c * 4)) ^ ((unsigned)(e0 & 7) << 4))));
                m1 = fmaxf(m1, *(const float*)(sB + e1 * 256 +
                             (((unsigned)(c * 4)) ^ ((unsigned)(e1 & 7) << 4))));
            }
            if (p < hi) {
                const int e0 = p - p0;
                m0 = fmaxf(m0, *(const float*)(sB + e0 * 256 +
                             (((unsigned)(c * 4)) ^ ((unsigned)(e0 & 7) << 4))));
            }
            float m = fmaxf(m0, m1);
            if (s0 >= p0 && s1 <= p1)
                out[(long)d * 64 + c] = m;                                   // sole owner
            else
                atomicMax((int*)out + (long)d * 64 + c, __float_as_int(m));  // boundary
        }
    }
}

extern "C" void kernel_launch(void* const* d_in, const int* in_sizes, int n_in,
                              void* d_out, int out_size, void* d_ws, size_t ws_size,
                              hipStream_t stream) {
    const float* x  = (const float*)d_in[0];
    const int*   ei = (const int*)d_in[1];
    const float* W1 = (const float*)d_in[2];
    const float* b1 = (const float*)d_in[3];
    const float* W2 = (const float*)d_in[4];
    const float* b2 = (const float*)d_in[5];
    float* out = (float*)d_out;

    const int E = in_sizes[1] / 2;
    const int N = in_sizes[0] / 64;

    int* wsI = (int*)d_ws;
    int* counts  = wsI + OFF_COUNTS;
    int* cursor  = wsI + OFF_CURSOR;
    int* starts  = wsI + OFF_STARTS;
    int* bsum    = wsI + OFF_BSUM;
    int2* csr    = (int2*)(wsI + OFF_CSR);
    unsigned short* wbf = (unsigned short*)(wsI + OFF_CSR + 2 * E);
    unsigned short* xbf = (unsigned short*)(wsI + OFF_CSR + 2 * E + WBF_DW);

    const long nOct = (long)N * 8;  // octets of 8 channels
    const size_t needed = ((size_t)(OFF_CSR + 2 * E) + WBF_DW + (size_t)N * 32) * 4;
    const int use_bf = (ws_size >= needed) ? 1 : 0;

    hipMemsetAsync(d_out, 0, (size_t)out_size * sizeof(float), stream);
    hipMemsetAsync(counts, 0, (size_t)N * sizeof(int), stream);

    const int nbP = 48 + (use_bf ? (int)((nOct + 255) / 256) : 0);
    prep_all_kernel<<<nbP, 256, 0, stream>>>(x, W1, W2, wbf, xbf, nOct, use_bf);

    const int nbH = (E / 4 + 255) / 256 + 1;
    hist_kernel<<<nbH, 256, 0, stream>>>(ei, counts, E);

    const int nb2 = (N + NSCAN - 1) / NSCAN;
    scanA_kernel<<<nb2, 256, 0, stream>>>(counts, bsum, N);
    scanB_kernel<<<1, 64, 0, stream>>>(bsum, starts, nb2, N, E);
    scanC_kernel<<<nb2, 256, 0, stream>>>(counts, bsum, starts, cursor, N);

    const int nbE = (E + 255) / 256;
    scatter_kernel<<<nbE, 256, 0, stream>>>(ei, cursor, csr, E);

    const int nb = (E + EB - 1) / EB;
    edgeconv_kernel<<<nb, 256, 0, stream>>>(x, use_bf ? xbf : (unsigned short*)nullptr,
                                            csr, starts, b1, b2, wbf, out, E, use_bf);
}

// Round 7
// 351.059 us; speedup vs baseline: 1.9171x; 1.2036x over previous
//
#include <hip/hip_runtime.h>
#include <hip/hip_bf16.h>

typedef __bf16 bf16x8 __attribute__((ext_vector_type(8)));
typedef __bf16 bf16x4 __attribute__((ext_vector_type(4)));
typedef float f32x4 __attribute__((ext_vector_type(4)));

#define EB 128    // edges per block
#define NSCAN 1024

// ---- ws layout (dword offsets) ----
#define OFF_COUNTS 0          // N dwords
#define OFF_STARTS 100000     // N+1 dwords
#define OFF_BSUM   200016     // ~128 dwords
#define OFF_SLOT   200160     // E dwords
// csr  (int2[E])      at OFF_SLOT + E
// wbf  (bf16[12288])  at OFF_SLOT + 3E          [6144 dwords]
// xbf  (bf16[N*64])   at OFF_SLOT + 3E + 6144   [N*32 dwords]
#define WBF_DW 6144

__device__ __forceinline__ unsigned short f2bf(float v) {
    unsigned int u = __float_as_uint(v);
    return (unsigned short)((u + 0x7fffu + ((u >> 16) & 1u)) >> 16);
}

__device__ __forceinline__ bf16x8 pack8(float4 a, float4 b) {
    bf16x8 r;
    r[0] = (__bf16)a.x; r[1] = (__bf16)a.y; r[2] = (__bf16)a.z; r[3] = (__bf16)a.w;
    r[4] = (__bf16)b.x; r[5] = (__bf16)b.y; r[6] = (__bf16)b.z; r[7] = (__bf16)b.w;
    return r;
}

// blocks [0,48): weight transpose+cvt; blocks [48, ...): x -> bf16
__global__ void prep_all_kernel(const float* __restrict__ x,
                                const float* __restrict__ W1,
                                const float* __restrict__ W2,
                                unsigned short* __restrict__ wbf,
                                unsigned short* __restrict__ xbf,
                                long nOct, int use_bf) {
    int b = blockIdx.x;
    if (b < 48) {
        int t = b * 256 + threadIdx.x;
        if (t < 8192) {
            int c = t >> 7, k = t & 127;
            wbf[t] = f2bf(W1[k * 64 + c]);
        } else if (t < 12288) {
            int i = t - 8192;
            int o = i >> 6, c = i & 63;
            wbf[t] = f2bf(W2[c * 64 + o]);
        }
    } else if (use_bf) {
        long i = (long)(b - 48) * 256 + threadIdx.x;   // octet index
        if (i < nOct) {
            float4 a = *(const float4*)(x + i * 8);
            float4 c = *(const float4*)(x + i * 8 + 4);
            *(bf16x8*)(xbf + i * 8) = pack8(a, c);
        }
    }
}

// histogram; atomicAdd return value IS the edge's slot within its dst segment
__global__ void hist_kernel(const int* __restrict__ ei, int* __restrict__ counts,
                            int* __restrict__ slot, int E) {
    int t = blockIdx.x * blockDim.x + threadIdx.x;
    int i = t * 4;
    if (i + 3 < E) {
        int4 d = *(const int4*)(ei + E + i);
        int4 s;
        s.x = atomicAdd(&counts[d.x], 1);
        s.y = atomicAdd(&counts[d.y], 1);
        s.z = atomicAdd(&counts[d.z], 1);
        s.w = atomicAdd(&counts[d.w], 1);
        *(int4*)(slot + i) = s;
    } else {
        for (int j = 0; j < 4 && i + j < E; ++j)
            slot[i + j] = atomicAdd(&counts[ei[E + i + j]], 1);
    }
}

__global__ void scanA_kernel(const int* __restrict__ counts, int* __restrict__ bsum, int N) {
    int b = blockIdx.x, t = threadIdx.x;
    int base = b * NSCAN + t * 4;
    int s = 0;
    #pragma unroll
    for (int q = 0; q < 4; ++q)
        if (base + q < N) s += counts[base + q];
    #pragma unroll
    for (int off = 1; off < 64; off <<= 1) s += __shfl_xor(s, off);
    __shared__ int wsum[4];
    if ((t & 63) == 0) wsum[t >> 6] = s;
    __syncthreads();
    if (t == 0) bsum[b] = wsum[0] + wsum[1] + wsum[2] + wsum[3];
}

// single wave; nb <= 128
__global__ void scanB_kernel(int* __restrict__ bsum, int* __restrict__ starts, int nb, int N, int E) {
    int lane = threadIdx.x;
    int v0 = (lane < nb) ? bsum[lane] : 0;
    int v1 = (64 + lane < nb) ? bsum[64 + lane] : 0;
    int s = v0;
    #pragma unroll
    for (int off = 1; off < 64; off <<= 1) {
        int n = __shfl_up(s, off);
        if (lane >= off) s += n;
    }
    int total0 = __shfl(s, 63);
    int s1 = v1;
    #pragma unroll
    for (int off = 1; off < 64; off <<= 1) {
        int n = __shfl_up(s1, off);
        if (lane >= off) s1 += n;
    }
    if (lane < nb) bsum[lane] = s - v0;
    if (64 + lane < nb) bsum[64 + lane] = total0 + s1 - v1;
    if (lane == 0) starts[N] = E;
}

__global__ void scanC_kernel(const int* __restrict__ counts, const int* __restrict__ bsum,
                             int* __restrict__ starts, int N) {
    int b = blockIdx.x, t = threadIdx.x;
    int lane = t & 63, w = t >> 6;
    int base = b * NSCAN + t * 4;
    int c[4];
    #pragma unroll
    for (int q = 0; q < 4; ++q)
        c[q] = (base + q < N) ? counts[base + q] : 0;
    int tot = c[0] + c[1] + c[2] + c[3];
    int inc = tot;
    #pragma unroll
    for (int off = 1; off < 64; off <<= 1) {
        int n = __shfl_up(inc, off);
        if (lane >= off) inc += n;
    }
    int excl = inc - tot;
    __shared__ int wtot[4];
    if (lane == 63) wtot[w] = inc;
    __syncthreads();
    int woff = 0;
    for (int i = 0; i < w; ++i) woff += wtot[i];
    int run = bsum[b] + woff + excl;
    #pragma unroll
    for (int q = 0; q < 4; ++q) {
        if (base + q < N) { starts[base + q] = run; run += c[q]; }
    }
}

// atomic-free scatter using precomputed slots
__global__ void scatter_kernel(const int* __restrict__ ei, const int* __restrict__ starts,
                               const int* __restrict__ slot, int2* __restrict__ csr, int E) {
    int t = blockIdx.x * blockDim.x + threadIdx.x;
    if (t < E) {
        int s = ei[t], d = ei[E + t];
        int p = starts[d] + slot[t];
        csr[p] = make_int2(s, d);
    }
}

__global__ __launch_bounds__(256, 6)
void edgeconv_kernel(const float* __restrict__ x,
                     const unsigned short* __restrict__ xbf,  // may be null
                     const int2* __restrict__ csr,
                     const int* __restrict__ starts,
                     const float* __restrict__ b1,
                     const float* __restrict__ b2,
                     const unsigned short* __restrict__ wbf,
                     float* __restrict__ out,
                     int E, int use_bf) {
    // sB (16KB): h1 bf16 [128][64] (rows 128B, XOR swizzle (e&7)<<4 on 16B
    // chunks). h2 (bf16, same layout) overlays the SAME rows — each wave
    // overwrites only its own rows, so no barrier until the cross-wave max.
    __shared__ __align__(16) unsigned char sB[EB * 128];

    const int tid  = threadIdx.x;         // 0..255 (4 waves)
    const int lane = tid & 63;
    const int w    = tid >> 6;            // wave 0..3
    const int ln   = lane & 15;
    const int rg   = lane >> 4;           // 0..3
    const int p0   = blockIdx.x * EB;
    const int p1   = min(p0 + EB, E);

    const bf16x8* wsv = (const bf16x8*)wbf;

    // ---------------- gather: B-fragments straight into registers ----------------
    bf16x8 fr[2][4];
    #pragma unroll
    for (int eti = 0; eti < 2; ++eti) {
        const int p = p0 + (w * 2 + eti) * 16 + ln;
        int2 sd = (p < E) ? csr[p] : make_int2(0, 0);
        if (use_bf) {
            const unsigned short* xi = xbf + (long)sd.y * 64;
            const unsigned short* xj = xbf + (long)sd.x * 64;
            bf16x8 xiA = *(const bf16x8*)(xi + rg * 8);
            bf16x8 xiB = *(const bf16x8*)(xi + 32 + rg * 8);
            bf16x8 xjA = *(const bf16x8*)(xj + rg * 8);
            bf16x8 xjB = *(const bf16x8*)(xj + 32 + rg * 8);
            fr[eti][0] = xiA;
            fr[eti][1] = xiB;
            #pragma unroll
            for (int j = 0; j < 8; ++j) {
                fr[eti][2][j] = (__bf16)((float)xjA[j] - (float)xiA[j]);
                fr[eti][3][j] = (__bf16)((float)xjB[j] - (float)xiB[j]);
            }
        } else {
            const float* xi = x + (long)sd.y * 64;
            const float* xj = x + (long)sd.x * 64;
            float4 a0 = *(const float4*)(xi + rg * 8),      a1 = *(const float4*)(xi + rg * 8 + 4);
            float4 a2 = *(const float4*)(xi + 32 + rg * 8), a3 = *(const float4*)(xi + 32 + rg * 8 + 4);
            float4 c0 = *(const float4*)(xj + rg * 8),      c1 = *(const float4*)(xj + rg * 8 + 4);
            float4 c2 = *(const float4*)(xj + 32 + rg * 8), c3 = *(const float4*)(xj + 32 + rg * 8 + 4);
            fr[eti][0] = pack8(a0, a1);
            fr[eti][1] = pack8(a2, a3);
            float4 d0, d1, d2, d3;
            d0.x = c0.x - a0.x; d0.y = c0.y - a0.y; d0.z = c0.z - a0.z; d0.w = c0.w - a0.w;
            d1.x = c1.x - a1.x; d1.y = c1.y - a1.y; d1.z = c1.z - a1.z; d1.w = c1.w - a1.w;
            d2.x = c2.x - a2.x; d2.y = c2.y - a2.y; d2.z = c2.z - a2.z; d2.w = c2.w - a2.w;
            d3.x = c3.x - a3.x; d3.y = c3.y - a3.y; d3.z = c3.z - a3.z; d3.w = c3.w - a3.w;
            fr[eti][2] = pack8(d0, d1);
            fr[eti][3] = pack8(d2, d3);
        }
    }

    // ---------------- GEMM1: H1^T = W1^T @ F^T (B from registers) ----------------
    f32x4 acc1[2][4];
    #pragma unroll
    for (int eti = 0; eti < 2; ++eti)
        #pragma unroll
        for (int ct = 0; ct < 4; ++ct)
            acc1[eti][ct] = (f32x4){0.f, 0.f, 0.f, 0.f};

    #pragma unroll
    for (int kt = 0; kt < 4; ++kt) {
        #pragma unroll
        for (int ct = 0; ct < 4; ++ct) {
            bf16x8 wf = wsv[(ct * 16 + ln) * 16 + kt * 4 + rg];
            acc1[0][ct] = __builtin_amdgcn_mfma_f32_16x16x32_bf16(wf, fr[0][kt], acc1[0][ct], 0, 0, 0);
            acc1[1][ct] = __builtin_amdgcn_mfma_f32_16x16x32_bf16(wf, fr[1][kt], acc1[1][ct], 0, 0, 0);
        }
    }

    // ---------------- epilogue1: bias+relu -> bf16 h1 -> sB (wave-local) ----------------
    #pragma unroll
    for (int eti = 0; eti < 2; ++eti) {
        const int e = (w * 2 + eti) * 16 + ln;
        unsigned char* rowp = sB + e * 128;
        const unsigned int swz = (unsigned int)(e & 7) << 4;
        #pragma unroll
        for (int ct = 0; ct < 4; ++ct) {
            const int c0 = ct * 16 + rg * 4;
            float4 bv = *(const float4*)(b1 + c0);
            bf16x4 hv;
            hv[0] = (__bf16)fmaxf(acc1[eti][ct][0] + bv.x, 0.f);
            hv[1] = (__bf16)fmaxf(acc1[eti][ct][1] + bv.y, 0.f);
            hv[2] = (__bf16)fmaxf(acc1[eti][ct][2] + bv.z, 0.f);
            hv[3] = (__bf16)fmaxf(acc1[eti][ct][3] + bv.w, 0.f);
            *(bf16x4*)(rowp + (((unsigned)(c0 * 2)) ^ swz)) = hv;
        }
    }

    // ---------------- GEMM2: H2^T = W2^T @ H1^T (h1 read is wave-local) ----------------
    f32x4 acc2[2][4];
    #pragma unroll
    for (int eti = 0; eti < 2; ++eti)
        #pragma unroll
        for (int ot = 0; ot < 4; ++ot)
            acc2[eti][ot] = (f32x4){0.f, 0.f, 0.f, 0.f};

    #pragma unroll
    for (int kt = 0; kt < 2; ++kt) {
        #pragma unroll
        for (int eti = 0; eti < 2; ++eti) {
            const int e = (w * 2 + eti) * 16 + ln;
            bf16x8 bfr = *(const bf16x8*)(sB + e * 128 +
                           (((unsigned)(kt * 64 + rg * 16)) ^ ((unsigned)(e & 7) << 4)));
            #pragma unroll
            for (int ot = 0; ot < 4; ++ot) {
                bf16x8 wf = wsv[1024 + (ot * 16 + ln) * 8 + kt * 4 + rg];
                acc2[eti][ot] = __builtin_amdgcn_mfma_f32_16x16x32_bf16(wf, bfr, acc2[eti][ot], 0, 0, 0);
            }
        }
    }

    // ---------------- epilogue2: bias+relu -> bf16 h2 overlaying own h1 rows ----------------
    #pragma unroll
    for (int eti = 0; eti < 2; ++eti) {
        const int e = (w * 2 + eti) * 16 + ln;
        unsigned char* rowp = sB + e * 128;
        const unsigned int swz = (unsigned int)(e & 7) << 4;
        #pragma unroll
        for (int ot = 0; ot < 4; ++ot) {
            const int c0 = ot * 16 + rg * 4;
            float4 bv = *(const float4*)(b2 + c0);
            bf16x4 hv;
            hv[0] = (__bf16)fmaxf(acc2[eti][ot][0] + bv.x, 0.f);
            hv[1] = (__bf16)fmaxf(acc2[eti][ot][1] + bv.y, 0.f);
            hv[2] = (__bf16)fmaxf(acc2[eti][ot][2] + bv.z, 0.f);
            hv[3] = (__bf16)fmaxf(acc2[eti][ot][3] + bv.w, 0.f);
            *(bf16x4*)(rowp + (((unsigned)(c0 * 2)) ^ swz)) = hv;
        }
    }

    __syncthreads();  // the only barrier: h2 must be visible cross-wave

    // ---------------- segmented max over dst groups ----------------
    {
        const int dfirst = csr[p0].y;
        const int dlast  = csr[p1 - 1].y;
        const int c = lane;
        for (int d = dfirst + w; d <= dlast; d += 4) {
            const int s0 = starts[d], s1 = starts[d + 1];
            const int lo = max(s0, p0), hi = min(s1, p1);
            if (lo >= hi) continue;  // zero-edge node inside range
            unsigned int m0 = 0, m1 = 0;  // bf16 bits; relu>=0 so bit-max == fp-max
            int p = lo;
            for (; p + 1 < hi; p += 2) {
                const int e0 = p - p0, e1 = e0 + 1;
                unsigned int v0 = *(const unsigned short*)(sB + e0 * 128 +
                                    (((unsigned)(c * 2)) ^ ((unsigned)(e0 & 7) << 4)));
                unsigned int v1 = *(const unsigned short*)(sB + e1 * 128 +
                                    (((unsigned)(c * 2)) ^ ((unsigned)(e1 & 7) << 4)));
                m0 = max(m0, v0);
                m1 = max(m1, v1);
            }
            if (p < hi) {
                const int e0 = p - p0;
                unsigned int v0 = *(const unsigned short*)(sB + e0 * 128 +
                                    (((unsigned)(c * 2)) ^ ((unsigned)(e0 & 7) << 4)));
                m0 = max(m0, v0);
            }
            float m = __uint_as_float(max(m0, m1) << 16);
            if (s0 >= p0 && s1 <= p1)
                out[(long)d * 64 + c] = m;                                   // sole owner
            else
                atomicMax((int*)out + (long)d * 64 + c, __float_as_int(m));  // boundary
        }
    }
}

extern "C" void kernel_launch(void* const* d_in, const int* in_sizes, int n_in,
                              void* d_out, int out_size, void* d_ws, size_t ws_size,
                              hipStream_t stream) {
    const float* x  = (const float*)d_in[0];
    const int*   ei = (const int*)d_in[1];
    const float* W1 = (const float*)d_in[2];
    const float* b1 = (const float*)d_in[3];
    const float* W2 = (const float*)d_in[4];
    const float* b2 = (const float*)d_in[5];
    float* out = (float*)d_out;

    const int E = in_sizes[1] / 2;
    const int N = in_sizes[0] / 64;

    int* wsI = (int*)d_ws;
    int* counts  = wsI + OFF_COUNTS;
    int* starts  = wsI + OFF_STARTS;
    int* bsum    = wsI + OFF_BSUM;
    int* slot    = wsI + OFF_SLOT;
    int2* csr    = (int2*)(wsI + OFF_SLOT + E);
    unsigned short* wbf = (unsigned short*)(wsI + OFF_SLOT + 3 * E);
    unsigned short* xbf = (unsigned short*)(wsI + OFF_SLOT + 3 * E + WBF_DW);

    const long nOct = (long)N * 8;  // octets of 8 channels
    const size_t needed = ((size_t)OFF_SLOT + 3u * (size_t)E + WBF_DW + (size_t)N * 32) * 4;
    const int use_bf = (ws_size >= needed) ? 1 : 0;

    hipMemsetAsync(d_out, 0, (size_t)out_size * sizeof(float), stream);
    hipMemsetAsync(counts, 0, (size_t)N * sizeof(int), stream);

    const int nbP = 48 + (use_bf ? (int)((nOct + 255) / 256) : 0);
    prep_all_kernel<<<nbP, 256, 0, stream>>>(x, W1, W2, wbf, xbf, nOct, use_bf);

    const int nbH = (E / 4 + 255) / 256 + 1;
    hist_kernel<<<nbH, 256, 0, stream>>>(ei, counts, slot, E);

    const int nb2 = (N + NSCAN - 1) / NSCAN;
    scanA_kernel<<<nb2, 256, 0, stream>>>(counts, bsum, N);
    scanB_kernel<<<1, 64, 0, stream>>>(bsum, starts, nb2, N, E);
    scanC_kernel<<<nb2, 256, 0, stream>>>(counts, bsum, starts, N);

    const int nbE = (E + 255) / 256;
    scatter_kernel<<<nbE, 256, 0, stream>>>(ei, starts, slot, csr, E);

    const int nb = (E + EB - 1) / EB;
    edgeconv_kernel<<<nb, 256, 0, stream>>>(x, use_bf ? xbf : (unsigned short*)nullptr,
                                            csr, starts, b1, b2, wbf, out, E, use_bf);
}